// Round 10
// baseline (86.702 us; speedup 1.0000x reference)
//
#include <hip/hip_runtime.h>
#include <hip/hip_fp16.h>
#include <math.h>
#include <string.h>

namespace {
constexpr int kB  = 16;
constexpr int kNV = 6890;
constexpr int kNF = 13776;
constexpr int kTF = 2 * kNF;                 // 27552 triangles per person-pair
constexpr int kP  = kB / 2;                  // 8 person-pairs
constexpr int kC  = 65536;
constexpr int kCPT = 4;                      // collisions per thread
constexpr int kSpan = 256 * kCPT;            // 1024 collisions per block
constexpr int kChunks    = kC / kSpan;       // 64 chunks per pair
constexpr int kPenBlocks = kP * kChunks;     // 512
constexpr int kBChunks   = (kTF + 255) / 256;   // 108
constexpr int kBuildBlocks = kP * kBChunks;  // 864
// fallback grid
constexpr int kChunksF    = kC / 256;        // 256
constexpr int kPenBlocksF = kP * kChunksF;   // 2048
// ws layout (bytes): sums[8] @0, counter @64, partials (fallback) @4096,
// 32-B/triangle records @65536
constexpr size_t kSumOff  = 0;
constexpr size_t kCntOff  = 64;
constexpr size_t kPartOff = 4096;
constexpr size_t kRecOff  = 65536;
constexpr size_t kRecSz   = (size_t)kP * kTF * 32;       // 7.05 MB
}
#define SIGMA_F 1e-4f
#define EPS_F   1e-9f
#define THRESH_F 2000.0f
#define WEIGHT_F 0.1f

__device__ __forceinline__ unsigned pack2h(float a, float b) {
    __half2 h = __floats2half2_rn(a, b);
    unsigned u; memcpy(&u, &h, 4); return u;
}
__device__ __forceinline__ float2 unpack2h(unsigned u) {
    __half2 h; memcpy(&h, &u, 4); return __half22float2(h);
}
// 14-bit fixed point over [-16,16): step 1/512 (== fp16 ulp at |x|~4)
__device__ __forceinline__ unsigned q14(float x) {
    float v = (x + 16.0f) * 512.0f;
    v = fminf(fmaxf(v, 0.0f), 16383.0f);
    return (unsigned)(v + 0.5f);
}
__device__ __forceinline__ float dq14(unsigned q) {
    return (float)q * (1.0f / 512.0f) - 16.0f;
}

// rec[g] = 32 B: uint4 frame {fp16 cx cy cz nx ny nz radius pad}
//               uint4 pack  {9 x 14-bit verts}
// Also zero-inits sums/counter for the fused pen ticket (stream order
// guarantees visibility: build completes before pen starts).
__global__ void __launch_bounds__(256)
build_kernel(const float* __restrict__ verts,
             const float* __restrict__ trans,
             const int*   __restrict__ faces,
             uint4* __restrict__ rec,
             float* __restrict__ sums,
             unsigned* __restrict__ counter) {
    if (blockIdx.x == 0 && threadIdx.x <= kP) {
        if (threadIdx.x < kP) sums[threadIdx.x] = 0.0f;
        else *counter = 0u;
    }
    int blk = blockIdx.x;
    int p = blk & 7;                          // same XCD as pen's pair-p readers
    int t = (blk >> 3) * 256 + threadIdx.x;
    if (t >= kTF) return;
    int half = (t >= kNF) ? 1 : 0;
    int b = 2 * p + half;
    int f = t - half * kNF;
    float tx = trans[3 * b + 0];
    float ty = trans[3 * b + 1];
    float tz = trans[3 * b + 2];
    float3 v[3];
#pragma unroll
    for (int k = 0; k < 3; ++k) {
        int vi = faces[3 * f + k];            // coalesced (t linear per block)
        const float* vp = verts + ((size_t)b * kNV + vi) * 3;
        v[k] = make_float3(vp[0] + tx, vp[1] + ty, vp[2] + tz);
    }
    // receiver cone frame (reference order of ops, f32)
    float e1x = v[1].x - v[0].x, e1y = v[1].y - v[0].y, e1z = v[1].z - v[0].z;
    float e2x = v[2].x - v[0].x, e2y = v[2].y - v[0].y, e2z = v[2].z - v[0].z;
    float nx = e1y * e2z - e1z * e2y;
    float ny = e1z * e2x - e1x * e2z;
    float nz = e1x * e2y - e1y * e2x;
    float nn = sqrtf(nx * nx + ny * ny + nz * nz) + EPS_F;
    nx /= nn; ny /= nn; nz /= nn;
    float cx = (v[0].x + v[1].x + v[2].x) / 3.0f;
    float cy = (v[0].y + v[1].y + v[2].y) / 3.0f;
    float cz = (v[0].z + v[1].z + v[2].z) / 3.0f;
    float r2m = 0.0f;
#pragma unroll
    for (int k = 0; k < 3; ++k) {
        float dx = v[k].x - cx, dy = v[k].y - cy, dz = v[k].z - cz;
        r2m = fmaxf(r2m, dx * dx + dy * dy + dz * dz);
    }
    float radius = sqrtf(r2m);

    int g = p * kTF + t;
    uint4 fr;
    fr.x = pack2h(cx, cy);
    fr.y = pack2h(cz, nx);
    fr.z = pack2h(ny, nz);
    fr.w = pack2h(radius, 0.0f);
    unsigned q[9];
    q[0] = q14(v[0].x); q[1] = q14(v[0].y); q[2] = q14(v[0].z);
    q[3] = q14(v[1].x); q[4] = q14(v[1].y); q[5] = q14(v[1].z);
    q[6] = q14(v[2].x); q[7] = q14(v[2].y); q[8] = q14(v[2].z);
    uint4 pk;
    pk.x = q[0] | (q[1] << 14) | (q[2] << 28);
    pk.y = (q[2] >> 4) | (q[3] << 10) | (q[4] << 24);
    pk.z = (q[4] >> 8) | (q[5] << 6) | (q[6] << 20);
    pk.w = (q[6] >> 12) | (q[7] << 2) | (q[8] << 16);
    rec[(size_t)g * 2]     = fr;
    rec[(size_t)g * 2 + 1] = pk;
}

// Pen: 4 collisions per thread, branchless loads; block reduce; one device
// atomicAdd per block into sums[p]; last-block ticket (release RMW on the
// counter — NO full threadfence, no L2 invalidate) computes the final loss.
__global__ void __launch_bounds__(256)
pen_kernel(const int* __restrict__ coll,
           const uint4* __restrict__ rec,
           float* __restrict__ sums,
           unsigned* __restrict__ counter,
           float* __restrict__ out) {
    int blk = blockIdx.x;
    int p = blk & 7;                           // XCD-pinned pair
    int i0 = (blk >> 3) * kSpan + threadIdx.x; // base collision
    const int2* cp = (const int2*)coll + (size_t)p * kC;
    const uint4* rb = rec + (size_t)p * kTF * 2;

    int2 c[kCPT];
#pragma unroll
    for (int j = 0; j < kCPT; ++j) c[j] = cp[i0 + 256 * j];

    uint4 fu[kCPT], pk[kCPT];
#pragma unroll
    for (int j = 0; j < kCPT; ++j) {
        fu[j] = rb[(size_t)c[j].y * 2];        // receiver frame
        pk[j] = rb[(size_t)c[j].x * 2 + 1];    // intruder packed verts
    }

    float local = 0.0f;
#pragma unroll
    for (int j = 0; j < kCPT; ++j) {
        float2 a0 = unpack2h(fu[j].x);
        float2 a1 = unpack2h(fu[j].y);
        float2 a2 = unpack2h(fu[j].z);
        float2 a3 = unpack2h(fu[j].w);
        float cx = a0.x, cy = a0.y, cz = a1.x;
        float nx = a1.y, ny = a2.x, nz = a2.y;
        float rad_eps = a3.x + EPS_F;
        uint4 q = pk[j];
        float ivx[3], ivy[3], ivz[3];
        ivx[0] = dq14(q.x & 0x3FFFu);
        ivy[0] = dq14((q.x >> 14) & 0x3FFFu);
        ivz[0] = dq14(((q.x >> 28) | (q.y << 4)) & 0x3FFFu);
        ivx[1] = dq14((q.y >> 10) & 0x3FFFu);
        ivy[1] = dq14(((q.y >> 24) | (q.z << 8)) & 0x3FFFu);
        ivz[1] = dq14((q.z >> 6) & 0x3FFFu);
        ivx[2] = dq14(((q.z >> 20) | (q.w << 12)) & 0x3FFFu);
        ivy[2] = dq14((q.w >> 2) & 0x3FFFu);
        ivz[2] = dq14((q.w >> 16) & 0x3FFFu);
        float acc = 0.0f;
#pragma unroll
        for (int k = 0; k < 3; ++k) {
            float dx = ivx[k] - cx, dy = ivy[k] - cy, dz = ivz[k] - cz;
            float d = dx * nx + dy * ny + dz * nz;
            float px = dx - d * nx, py = dy - d * ny, pz = dz - d * nz;
            float radial = sqrtf(px * px + py * py + pz * pz);
            float fa = fmaxf(-d / SIGMA_F, 0.0f);
            float fb = fmaxf(1.0f - radial / rad_eps, 0.0f);
            float fd = fa * fb;
            acc += fd * fd;
        }
        local += (c[j].x != c[j].y) ? acc : 0.0f;
    }

#pragma unroll
    for (int off = 32; off > 0; off >>= 1)
        local += __shfl_down(local, off, 64);
    __shared__ float red[4];
    int lane = threadIdx.x & 63;
    int wid  = threadIdx.x >> 6;
    if (lane == 0) red[wid] = local;
    __syncthreads();
    if (threadIdx.x == 0) {
        float s = red[0] + red[1] + red[2] + red[3];
        atomicAdd(&sums[p], s);               // device-scope RMW, coherent
        // release orders the sums RMW before the ticket increment
        unsigned old = __hip_atomic_fetch_add(counter, 1u,
                                              __ATOMIC_RELEASE,
                                              __HIP_MEMORY_SCOPE_AGENT);
        if (old == (unsigned)(kPenBlocks - 1)) {
            // winner: all 511 other sums-RMWs are complete at the coherent
            // point; read via RMW (returns old) — no cache concerns.
            float cnt = 0.0f, vals = 0.0f;
#pragma unroll
            for (int qq = 0; qq < kP; ++qq) {
                float pq = atomicAdd(&sums[qq], 0.0f);
                if (pq < THRESH_F) {          // ordered cmp: NaN contributes 0
                    cnt += 1.0f;
                    vals += 1.0f / (1.0f + expf(-pq / THRESH_F)) - 0.5f;
                }
            }
            float loss = (cnt > 0.0f) ? (vals / fmaxf(cnt, 1.0f)) : 0.0f;
            out[0] = loss * WEIGHT_F;
        }
    }
}

// ---------- fallback (ws too small): R5 direct-gather + finalize ----------
__device__ __forceinline__ float cone_pair_loss(
    float3 r0, float3 r1, float3 r2, float3 i0, float3 i1, float3 i2) {
    float e1x = r1.x - r0.x, e1y = r1.y - r0.y, e1z = r1.z - r0.z;
    float e2x = r2.x - r0.x, e2y = r2.y - r0.y, e2z = r2.z - r0.z;
    float nx = e1y * e2z - e1z * e2y;
    float ny = e1z * e2x - e1x * e2z;
    float nz = e1x * e2y - e1y * e2x;
    float nn = sqrtf(nx * nx + ny * ny + nz * nz) + EPS_F;
    nx /= nn; ny /= nn; nz /= nn;
    float cx = (r0.x + r1.x + r2.x) / 3.0f;
    float cy = (r0.y + r1.y + r2.y) / 3.0f;
    float cz = (r0.z + r1.z + r2.z) / 3.0f;
    float r2m = 0.0f;
    {
        float dx = r0.x - cx, dy = r0.y - cy, dz = r0.z - cz;
        r2m = fmaxf(r2m, dx * dx + dy * dy + dz * dz);
        dx = r1.x - cx; dy = r1.y - cy; dz = r1.z - cz;
        r2m = fmaxf(r2m, dx * dx + dy * dy + dz * dz);
        dx = r2.x - cx; dy = r2.y - cy; dz = r2.z - cz;
        r2m = fmaxf(r2m, dx * dx + dy * dy + dz * dz);
    }
    float rad_eps = sqrtf(r2m) + EPS_F;
    float3 iv[3] = {i0, i1, i2};
    float acc = 0.0f;
#pragma unroll
    for (int k = 0; k < 3; ++k) {
        float dx = iv[k].x - cx, dy = iv[k].y - cy, dz = iv[k].z - cz;
        float d = dx * nx + dy * ny + dz * nz;
        float px = dx - d * nx, py = dy - d * ny, pz = dz - d * nz;
        float radial = sqrtf(px * px + py * py + pz * pz);
        float fa = fmaxf(-d / SIGMA_F, 0.0f);
        float fb = fmaxf(1.0f - radial / rad_eps, 0.0f);
        float fd = fa * fb;
        acc += fd * fd;
    }
    return acc;
}

__global__ void __launch_bounds__(256)
pen_direct(const int* __restrict__ coll,
           const float* __restrict__ verts,
           const float* __restrict__ trans,
           const int* __restrict__ faces,
           float* __restrict__ partials) {
    int blk = blockIdx.x;
    int p = blk & 7;
    int i = (blk >> 3) * 256 + threadIdx.x;
    int2 idx = ((const int2*)coll)[(size_t)p * kC + i];
    const float t0x = trans[6 * p + 0], t0y = trans[6 * p + 1], t0z = trans[6 * p + 2];
    const float t1x = trans[6 * p + 3], t1y = trans[6 * p + 4], t1z = trans[6 * p + 5];
    float local = 0.0f;
    if (idx.x != idx.y) {
        int hi = (idx.x >= kNF) ? 1 : 0;
        int hr = (idx.y >= kNF) ? 1 : 0;
        const int* fi = faces + 3 * (idx.x - hi * kNF);
        const int* fr = faces + 3 * (idx.y - hr * kNF);
        int vi0 = fi[0], vi1 = fi[1], vi2 = fi[2];
        int vr0 = fr[0], vr1 = fr[1], vr2 = fr[2];
        size_t bi = (size_t)(2 * p + hi) * kNV;
        size_t br = (size_t)(2 * p + hr) * kNV;
        float tix = hi ? t1x : t0x, tiy = hi ? t1y : t0y, tiz = hi ? t1z : t0z;
        float trx = hr ? t1x : t0x, try_ = hr ? t1y : t0y, trz = hr ? t1z : t0z;
        const float* q;
        q = verts + (bi + vi0) * 3; float3 i0 = make_float3(q[0] + tix, q[1] + tiy, q[2] + tiz);
        q = verts + (bi + vi1) * 3; float3 i1 = make_float3(q[0] + tix, q[1] + tiy, q[2] + tiz);
        q = verts + (bi + vi2) * 3; float3 i2 = make_float3(q[0] + tix, q[1] + tiy, q[2] + tiz);
        q = verts + (br + vr0) * 3; float3 r0 = make_float3(q[0] + trx, q[1] + try_, q[2] + trz);
        q = verts + (br + vr1) * 3; float3 r1 = make_float3(q[0] + trx, q[1] + try_, q[2] + trz);
        q = verts + (br + vr2) * 3; float3 r2 = make_float3(q[0] + trx, q[1] + try_, q[2] + trz);
        local = cone_pair_loss(r0, r1, r2, i0, i1, i2);
    }
#pragma unroll
    for (int off = 32; off > 0; off >>= 1)
        local += __shfl_down(local, off, 64);
    __shared__ float red[4];
    int lane = threadIdx.x & 63;
    int wid  = threadIdx.x >> 6;
    if (lane == 0) red[wid] = local;
    __syncthreads();
    if (threadIdx.x == 0)
        partials[blk] = red[0] + red[1] + red[2] + red[3];
}

__global__ void __launch_bounds__(512)
finalize_kernel(const float* __restrict__ partials, float* __restrict__ out, int chunks) {
    int wv = threadIdx.x >> 6;
    int lane = threadIdx.x & 63;
    float s = 0.0f;
    for (int j = lane; j < chunks; j += 64)
        s += partials[wv + 8 * j];
#pragma unroll
    for (int off = 32; off > 0; off >>= 1)
        s += __shfl_down(s, off, 64);
    __shared__ float pen[kP];
    if (lane == 0) pen[wv] = s;
    __syncthreads();
    if (threadIdx.x == 0) {
        float cnt = 0.0f, vals = 0.0f;
#pragma unroll
        for (int q = 0; q < kP; ++q) {
            float pq = pen[q];
            if (pq < THRESH_F) {
                cnt += 1.0f;
                vals += 1.0f / (1.0f + expf(-pq / THRESH_F)) - 0.5f;
            }
        }
        float loss = (cnt > 0.0f) ? (vals / fmaxf(cnt, 1.0f)) : 0.0f;
        out[0] = loss * WEIGHT_F;
    }
}
// --------------------------------------------------------------------------

extern "C" void kernel_launch(void* const* d_in, const int* in_sizes, int n_in,
                              void* d_out, int out_size, void* d_ws, size_t ws_size,
                              hipStream_t stream) {
    const float* verts = (const float*)d_in[0];
    const float* trans = (const float*)d_in[1];
    const int*   faces = (const int*)d_in[2];
    const int*   coll  = (const int*)d_in[3];
    float* out = (float*)d_out;

    if (ws_size >= kRecOff + kRecSz) {
        float*    sums    = (float*)((char*)d_ws + kSumOff);
        unsigned* counter = (unsigned*)((char*)d_ws + kCntOff);
        uint4*    rec     = (uint4*)((char*)d_ws + kRecOff);
        build_kernel<<<kBuildBlocks, 256, 0, stream>>>(verts, trans, faces,
                                                       rec, sums, counter);
        pen_kernel<<<kPenBlocks, 256, 0, stream>>>(coll, rec, sums, counter, out);
    } else {
        float* partials = (float*)((char*)d_ws + kPartOff);
        pen_direct<<<kPenBlocksF, 256, 0, stream>>>(coll, verts, trans, faces, partials);
        finalize_kernel<<<1, 512, 0, stream>>>(partials, out, kChunksF);
    }
}

// Round 11
// 79.730 us; speedup vs baseline: 1.0874x; 1.0874x over previous
//
#include <hip/hip_runtime.h>
#include <hip/hip_fp16.h>
#include <math.h>
#include <string.h>

namespace {
constexpr int kB  = 16;
constexpr int kNV = 6890;
constexpr int kNF = 13776;
constexpr int kTF = 2 * kNF;                 // 27552 triangles per person-pair
constexpr int kP  = kB / 2;                  // 8 person-pairs
constexpr int kC  = 65536;
constexpr int kCPT = 4;                      // collisions per thread
constexpr int kSpan = 256 * kCPT;            // 1024 collisions per block
constexpr int kChunks    = kC / kSpan;       // 64 chunks per pair
constexpr int kPenBlocks = kP * kChunks;     // 512
constexpr int kBChunks   = (kTF + 255) / 256;   // 108
constexpr int kBuildBlocks = kP * kBChunks;  // 864
// fallback grid
constexpr int kChunksF    = kC / 256;        // 256
constexpr int kPenBlocksF = kP * kChunksF;   // 2048
// ws layout (bytes): partials then 32-B/triangle records
constexpr size_t kPartOff = 0;                           // <=2048 floats
constexpr size_t kRecOff  = 65536;
constexpr size_t kRecSz   = (size_t)kP * kTF * 32;       // 7.05 MB
}
#define SIGMA_F 1e-4f
#define EPS_F   1e-9f
#define THRESH_F 2000.0f
#define WEIGHT_F 0.1f

// NOTE (twice-measured): do NOT fuse the finalize into pen with a ticket.
// Any cross-block release/fence (R3 __threadfence, R10 agent-scope release
// RMW) forces per-XCD L2 writebacks that thrash the gather stream:
// R3 56 us pen, R10 +8 us total. Two dispatches via stream order is cheaper.

__device__ __forceinline__ unsigned pack2h(float a, float b) {
    __half2 h = __floats2half2_rn(a, b);
    unsigned u; memcpy(&u, &h, 4); return u;
}
__device__ __forceinline__ float2 unpack2h(unsigned u) {
    __half2 h; memcpy(&h, &u, 4); return __half22float2(h);
}
// 14-bit fixed point over [-16,16): step 1/512 (== fp16 ulp at |x|~4)
__device__ __forceinline__ unsigned q14(float x) {
    float v = (x + 16.0f) * 512.0f;
    v = fminf(fmaxf(v, 0.0f), 16383.0f);
    return (unsigned)(v + 0.5f);
}
__device__ __forceinline__ float dq14(unsigned q) {
    return (float)q * (1.0f / 512.0f) - 16.0f;
}

// rec[g] = 32 B: uint4 frame {fp16 cx cy cz nx ny nz radius pad}
//               uint4 pack  {9 x 14-bit verts}
__global__ void __launch_bounds__(256)
build_kernel(const float* __restrict__ verts,
             const float* __restrict__ trans,
             const int*   __restrict__ faces,
             uint4* __restrict__ rec) {
    int blk = blockIdx.x;
    int p = blk & 7;                          // same XCD as pen's pair-p readers
    int t = (blk >> 3) * 256 + threadIdx.x;
    if (t >= kTF) return;
    int half = (t >= kNF) ? 1 : 0;
    int b = 2 * p + half;
    int f = t - half * kNF;
    float tx = trans[3 * b + 0];
    float ty = trans[3 * b + 1];
    float tz = trans[3 * b + 2];
    float3 v[3];
#pragma unroll
    for (int k = 0; k < 3; ++k) {
        int vi = faces[3 * f + k];            // coalesced (t linear per block)
        const float* vp = verts + ((size_t)b * kNV + vi) * 3;
        v[k] = make_float3(vp[0] + tx, vp[1] + ty, vp[2] + tz);
    }
    // receiver cone frame (reference order of ops, f32)
    float e1x = v[1].x - v[0].x, e1y = v[1].y - v[0].y, e1z = v[1].z - v[0].z;
    float e2x = v[2].x - v[0].x, e2y = v[2].y - v[0].y, e2z = v[2].z - v[0].z;
    float nx = e1y * e2z - e1z * e2y;
    float ny = e1z * e2x - e1x * e2z;
    float nz = e1x * e2y - e1y * e2x;
    float nn = sqrtf(nx * nx + ny * ny + nz * nz) + EPS_F;
    nx /= nn; ny /= nn; nz /= nn;
    float cx = (v[0].x + v[1].x + v[2].x) / 3.0f;
    float cy = (v[0].y + v[1].y + v[2].y) / 3.0f;
    float cz = (v[0].z + v[1].z + v[2].z) / 3.0f;
    float r2m = 0.0f;
#pragma unroll
    for (int k = 0; k < 3; ++k) {
        float dx = v[k].x - cx, dy = v[k].y - cy, dz = v[k].z - cz;
        r2m = fmaxf(r2m, dx * dx + dy * dy + dz * dz);
    }
    float radius = sqrtf(r2m);

    int g = p * kTF + t;
    uint4 fr;
    fr.x = pack2h(cx, cy);
    fr.y = pack2h(cz, nx);
    fr.z = pack2h(ny, nz);
    fr.w = pack2h(radius, 0.0f);
    unsigned q[9];
    q[0] = q14(v[0].x); q[1] = q14(v[0].y); q[2] = q14(v[0].z);
    q[3] = q14(v[1].x); q[4] = q14(v[1].y); q[5] = q14(v[1].z);
    q[6] = q14(v[2].x); q[7] = q14(v[2].y); q[8] = q14(v[2].z);
    uint4 pk;
    pk.x = q[0] | (q[1] << 14) | (q[2] << 28);
    pk.y = (q[2] >> 4) | (q[3] << 10) | (q[4] << 24);
    pk.z = (q[4] >> 8) | (q[5] << 6) | (q[6] << 20);
    pk.w = (q[6] >> 12) | (q[7] << 2) | (q[8] << 16);
    rec[(size_t)g * 2]     = fr;
    rec[(size_t)g * 2 + 1] = pk;
}

// Pen: 4 collisions per thread, fully branchless loads (indices always
// in-bounds; validity applied as a select) so all 8 scattered uint4 loads
// issue back-to-back per thread. One partial per block, no atomics.
__global__ void __launch_bounds__(256)
pen_kernel(const int* __restrict__ coll,
           const uint4* __restrict__ rec,
           float* __restrict__ partials) {
    int blk = blockIdx.x;
    int p = blk & 7;                           // XCD-pinned pair
    int i0 = (blk >> 3) * kSpan + threadIdx.x; // base collision
    const int2* cp = (const int2*)coll + (size_t)p * kC;
    const uint4* rb = rec + (size_t)p * kTF * 2;

    int2 c[kCPT];
#pragma unroll
    for (int j = 0; j < kCPT; ++j) c[j] = cp[i0 + 256 * j];

    uint4 fu[kCPT], pk[kCPT];
#pragma unroll
    for (int j = 0; j < kCPT; ++j) {
        fu[j] = rb[(size_t)c[j].y * 2];        // receiver frame
        pk[j] = rb[(size_t)c[j].x * 2 + 1];    // intruder packed verts
    }

    float local = 0.0f;
#pragma unroll
    for (int j = 0; j < kCPT; ++j) {
        float2 a0 = unpack2h(fu[j].x);
        float2 a1 = unpack2h(fu[j].y);
        float2 a2 = unpack2h(fu[j].z);
        float2 a3 = unpack2h(fu[j].w);
        float cx = a0.x, cy = a0.y, cz = a1.x;
        float nx = a1.y, ny = a2.x, nz = a2.y;
        float rad_eps = a3.x + EPS_F;
        uint4 q = pk[j];
        float ivx[3], ivy[3], ivz[3];
        ivx[0] = dq14(q.x & 0x3FFFu);
        ivy[0] = dq14((q.x >> 14) & 0x3FFFu);
        ivz[0] = dq14(((q.x >> 28) | (q.y << 4)) & 0x3FFFu);
        ivx[1] = dq14((q.y >> 10) & 0x3FFFu);
        ivy[1] = dq14(((q.y >> 24) | (q.z << 8)) & 0x3FFFu);
        ivz[1] = dq14((q.z >> 6) & 0x3FFFu);
        ivx[2] = dq14(((q.z >> 20) | (q.w << 12)) & 0x3FFFu);
        ivy[2] = dq14((q.w >> 2) & 0x3FFFu);
        ivz[2] = dq14((q.w >> 16) & 0x3FFFu);
        float acc = 0.0f;
#pragma unroll
        for (int k = 0; k < 3; ++k) {
            float dx = ivx[k] - cx, dy = ivy[k] - cy, dz = ivz[k] - cz;
            float d = dx * nx + dy * ny + dz * nz;
            float px = dx - d * nx, py = dy - d * ny, pz = dz - d * nz;
            float radial = sqrtf(px * px + py * py + pz * pz);
            float fa = fmaxf(-d / SIGMA_F, 0.0f);
            float fb = fmaxf(1.0f - radial / rad_eps, 0.0f);
            float fd = fa * fb;
            acc += fd * fd;
        }
        local += (c[j].x != c[j].y) ? acc : 0.0f;
    }

#pragma unroll
    for (int off = 32; off > 0; off >>= 1)
        local += __shfl_down(local, off, 64);
    __shared__ float red[4];
    int lane = threadIdx.x & 63;
    int wid  = threadIdx.x >> 6;
    if (lane == 0) red[wid] = local;
    __syncthreads();
    if (threadIdx.x == 0)
        partials[blk] = red[0] + red[1] + red[2] + red[3];
}

// ---------- fallback (ws too small): R5 direct-gather kernel ----------
__device__ __forceinline__ float cone_pair_loss(
    float3 r0, float3 r1, float3 r2, float3 i0, float3 i1, float3 i2) {
    float e1x = r1.x - r0.x, e1y = r1.y - r0.y, e1z = r1.z - r0.z;
    float e2x = r2.x - r0.x, e2y = r2.y - r0.y, e2z = r2.z - r0.z;
    float nx = e1y * e2z - e1z * e2y;
    float ny = e1z * e2x - e1x * e2z;
    float nz = e1x * e2y - e1y * e2x;
    float nn = sqrtf(nx * nx + ny * ny + nz * nz) + EPS_F;
    nx /= nn; ny /= nn; nz /= nn;
    float cx = (r0.x + r1.x + r2.x) / 3.0f;
    float cy = (r0.y + r1.y + r2.y) / 3.0f;
    float cz = (r0.z + r1.z + r2.z) / 3.0f;
    float r2m = 0.0f;
    {
        float dx = r0.x - cx, dy = r0.y - cy, dz = r0.z - cz;
        r2m = fmaxf(r2m, dx * dx + dy * dy + dz * dz);
        dx = r1.x - cx; dy = r1.y - cy; dz = r1.z - cz;
        r2m = fmaxf(r2m, dx * dx + dy * dy + dz * dz);
        dx = r2.x - cx; dy = r2.y - cy; dz = r2.z - cz;
        r2m = fmaxf(r2m, dx * dx + dy * dy + dz * dz);
    }
    float rad_eps = sqrtf(r2m) + EPS_F;
    float3 iv[3] = {i0, i1, i2};
    float acc = 0.0f;
#pragma unroll
    for (int k = 0; k < 3; ++k) {
        float dx = iv[k].x - cx, dy = iv[k].y - cy, dz = iv[k].z - cz;
        float d = dx * nx + dy * ny + dz * nz;
        float px = dx - d * nx, py = dy - d * ny, pz = dz - d * nz;
        float radial = sqrtf(px * px + py * py + pz * pz);
        float fa = fmaxf(-d / SIGMA_F, 0.0f);
        float fb = fmaxf(1.0f - radial / rad_eps, 0.0f);
        float fd = fa * fb;
        acc += fd * fd;
    }
    return acc;
}

__global__ void __launch_bounds__(256)
pen_direct(const int* __restrict__ coll,
           const float* __restrict__ verts,
           const float* __restrict__ trans,
           const int* __restrict__ faces,
           float* __restrict__ partials) {
    int blk = blockIdx.x;
    int p = blk & 7;
    int i = (blk >> 3) * 256 + threadIdx.x;
    int2 idx = ((const int2*)coll)[(size_t)p * kC + i];
    const float t0x = trans[6 * p + 0], t0y = trans[6 * p + 1], t0z = trans[6 * p + 2];
    const float t1x = trans[6 * p + 3], t1y = trans[6 * p + 4], t1z = trans[6 * p + 5];
    float local = 0.0f;
    if (idx.x != idx.y) {
        int hi = (idx.x >= kNF) ? 1 : 0;
        int hr = (idx.y >= kNF) ? 1 : 0;
        const int* fi = faces + 3 * (idx.x - hi * kNF);
        const int* fr = faces + 3 * (idx.y - hr * kNF);
        int vi0 = fi[0], vi1 = fi[1], vi2 = fi[2];
        int vr0 = fr[0], vr1 = fr[1], vr2 = fr[2];
        size_t bi = (size_t)(2 * p + hi) * kNV;
        size_t br = (size_t)(2 * p + hr) * kNV;
        float tix = hi ? t1x : t0x, tiy = hi ? t1y : t0y, tiz = hi ? t1z : t0z;
        float trx = hr ? t1x : t0x, try_ = hr ? t1y : t0y, trz = hr ? t1z : t0z;
        const float* q;
        q = verts + (bi + vi0) * 3; float3 i0 = make_float3(q[0] + tix, q[1] + tiy, q[2] + tiz);
        q = verts + (bi + vi1) * 3; float3 i1 = make_float3(q[0] + tix, q[1] + tiy, q[2] + tiz);
        q = verts + (bi + vi2) * 3; float3 i2 = make_float3(q[0] + tix, q[1] + tiy, q[2] + tiz);
        q = verts + (br + vr0) * 3; float3 r0 = make_float3(q[0] + trx, q[1] + try_, q[2] + trz);
        q = verts + (br + vr1) * 3; float3 r1 = make_float3(q[0] + trx, q[1] + try_, q[2] + trz);
        q = verts + (br + vr2) * 3; float3 r2 = make_float3(q[0] + trx, q[1] + try_, q[2] + trz);
        local = cone_pair_loss(r0, r1, r2, i0, i1, i2);
    }
#pragma unroll
    for (int off = 32; off > 0; off >>= 1)
        local += __shfl_down(local, off, 64);
    __shared__ float red[4];
    int lane = threadIdx.x & 63;
    int wid  = threadIdx.x >> 6;
    if (lane == 0) red[wid] = local;
    __syncthreads();
    if (threadIdx.x == 0)
        partials[blk] = red[0] + red[1] + red[2] + red[3];
}
// ----------------------------------------------------------------------

// 1 block, 512 threads = 8 waves; wave w reduces pair w's `chunks` partials.
// NaN-proof: ordered compare decides keep; NaN pen contributes nothing.
__global__ void __launch_bounds__(512)
finalize_kernel(const float* __restrict__ partials, float* __restrict__ out, int chunks) {
    int wv = threadIdx.x >> 6;
    int lane = threadIdx.x & 63;
    float s = 0.0f;
    for (int j = lane; j < chunks; j += 64)
        s += partials[wv + 8 * j];
#pragma unroll
    for (int off = 32; off > 0; off >>= 1)
        s += __shfl_down(s, off, 64);
    __shared__ float pen[kP];
    if (lane == 0) pen[wv] = s;
    __syncthreads();
    if (threadIdx.x == 0) {
        float cnt = 0.0f, vals = 0.0f;
#pragma unroll
        for (int q = 0; q < kP; ++q) {
            float pq = pen[q];
            if (pq < THRESH_F) {
                cnt += 1.0f;
                vals += 1.0f / (1.0f + expf(-pq / THRESH_F)) - 0.5f;
            }
        }
        float loss = (cnt > 0.0f) ? (vals / fmaxf(cnt, 1.0f)) : 0.0f;
        out[0] = loss * WEIGHT_F;
    }
}

extern "C" void kernel_launch(void* const* d_in, const int* in_sizes, int n_in,
                              void* d_out, int out_size, void* d_ws, size_t ws_size,
                              hipStream_t stream) {
    const float* verts = (const float*)d_in[0];
    const float* trans = (const float*)d_in[1];
    const int*   faces = (const int*)d_in[2];
    const int*   coll  = (const int*)d_in[3];
    float* out      = (float*)d_out;
    float* partials = (float*)((char*)d_ws + kPartOff);

    if (ws_size >= kRecOff + kRecSz) {
        uint4* rec = (uint4*)((char*)d_ws + kRecOff);
        build_kernel<<<kBuildBlocks, 256, 0, stream>>>(verts, trans, faces, rec);
        pen_kernel<<<kPenBlocks, 256, 0, stream>>>(coll, rec, partials);
        finalize_kernel<<<1, 512, 0, stream>>>(partials, out, kChunks);
    } else {
        pen_direct<<<kPenBlocksF, 256, 0, stream>>>(coll, verts, trans, faces, partials);
        finalize_kernel<<<1, 512, 0, stream>>>(partials, out, kChunksF);
    }
}